// Round 7
// baseline (11493.646 us; speedup 1.0000x reference)
//
#include <hip/hip_runtime.h>
#include <math.h>
#include <stddef.h>

// Problem constants
#define VOCAB 50000
#define EMB   1024
#define H2    512
#define R4    2048      // 4*H2 gate rows per direction
#define TLEN  4096
#define NTAGS 5
#define STARTT 3
#define STOPT  4
#define NEGV  (-10000.0f)

#define DWG   32        // workgroups per direction in recurrence
#define SLICE 16        // h-elements per WG (512/32)

typedef unsigned long long u64;

#define ASTORE64(p,v) __hip_atomic_store((p), (v), __ATOMIC_RELAXED, __HIP_MEMORY_SCOPE_AGENT)

// Fast activations: v_exp_f32 + v_rcp_f32. Rel err ~1e-6. Arithmetic kept
// identical to rounds 4/5 (round-5's reduction-order change flipped one
// near-tie Viterbi tag; no further drift).
__device__ __forceinline__ float fsig(float x) {
    return __builtin_amdgcn_rcpf(1.f + __expf(-x));
}
__device__ __forceinline__ float ftanh(float x) {
    return 1.f - 2.f * __builtin_amdgcn_rcpf(1.f + __expf(2.f * x));
}

// -------------------------------------------------------------------------
// Single-detector pipelined spin, NO ENTRY DRAIN. At entry, wave-0's older
// vmem (leftover polls: done; G loads: done; fresh mailbox/hsd store-acks:
// ~400cyc remaining) is NOT waited on serially; groups A/B are issued
// immediately and the first s_waitcnt vmcnt(4) covers the older ops
// CONCURRENTLY with A's flight (vmcnt completes in issue order: everything
// older than B done => A landed).
// Steady state: alternate {check A, reissue A, wait B} / {check B, reissue
// B, wait A} with vmcnt(4) — invariant: before each check of X, outstanding
// = [X(4), Y(4)] (plus nothing older), so vmcnt(4) lands exactly X. Exit
// leaves one group (4) in flight; callers must NOT use __syncthreads (its
// vmcnt(0) would drain it — the round-4/5 hidden ~400cyc/step cost).
// Clobbers v[32:63], s[20:21].
// -------------------------------------------------------------------------
__device__ __forceinline__ void spin64(const u64* p, unsigned want,
    unsigned& h0, unsigned& h1, unsigned& h2, unsigned& h3,
    unsigned& h4, unsigned& h5, unsigned& h6, unsigned& h7)
{
    asm volatile(
        "global_load_dwordx4 v[32:35], %[p], off sc1\n\t"
        "global_load_dwordx4 v[36:39], %[p], off offset:16 sc1\n\t"
        "global_load_dwordx4 v[40:43], %[p], off offset:32 sc1\n\t"
        "global_load_dwordx4 v[44:47], %[p], off offset:48 sc1\n\t"
        "s_sleep 1\n\t"                     // stagger A/B sampling instants
        "global_load_dwordx4 v[48:51], %[p], off sc1\n\t"
        "global_load_dwordx4 v[52:55], %[p], off offset:16 sc1\n\t"
        "global_load_dwordx4 v[56:59], %[p], off offset:32 sc1\n\t"
        "global_load_dwordx4 v[60:63], %[p], off offset:48 sc1\n\t"
        "1:\n\t"
        "s_waitcnt vmcnt(4)\n\t"            // older-than-B done => A landed
        "v_cmp_eq_u32 vcc, %[w], v33\n\t"
        "v_cmp_eq_u32 s[20:21], %[w], v35\n\t"
        "s_and_b64 vcc, vcc, s[20:21]\n\t"
        "v_cmp_eq_u32 s[20:21], %[w], v37\n\t"
        "s_and_b64 vcc, vcc, s[20:21]\n\t"
        "v_cmp_eq_u32 s[20:21], %[w], v39\n\t"
        "s_and_b64 vcc, vcc, s[20:21]\n\t"
        "v_cmp_eq_u32 s[20:21], %[w], v41\n\t"
        "s_and_b64 vcc, vcc, s[20:21]\n\t"
        "v_cmp_eq_u32 s[20:21], %[w], v43\n\t"
        "s_and_b64 vcc, vcc, s[20:21]\n\t"
        "v_cmp_eq_u32 s[20:21], %[w], v45\n\t"
        "s_and_b64 vcc, vcc, s[20:21]\n\t"
        "v_cmp_eq_u32 s[20:21], %[w], v47\n\t"
        "s_and_b64 vcc, vcc, s[20:21]\n\t"
        "s_andn2_b64 s[20:21], exec, vcc\n\t"
        "s_cbranch_scc0 3f\n\t"             // all lanes, all tags -> A valid
        "global_load_dwordx4 v[32:35], %[p], off sc1\n\t"
        "global_load_dwordx4 v[36:39], %[p], off offset:16 sc1\n\t"
        "global_load_dwordx4 v[40:43], %[p], off offset:32 sc1\n\t"
        "global_load_dwordx4 v[44:47], %[p], off offset:48 sc1\n\t"
        "s_waitcnt vmcnt(4)\n\t"            // outstanding [B, A'] -> B landed
        "v_cmp_eq_u32 vcc, %[w], v49\n\t"
        "v_cmp_eq_u32 s[20:21], %[w], v51\n\t"
        "s_and_b64 vcc, vcc, s[20:21]\n\t"
        "v_cmp_eq_u32 s[20:21], %[w], v53\n\t"
        "s_and_b64 vcc, vcc, s[20:21]\n\t"
        "v_cmp_eq_u32 s[20:21], %[w], v55\n\t"
        "s_and_b64 vcc, vcc, s[20:21]\n\t"
        "v_cmp_eq_u32 s[20:21], %[w], v57\n\t"
        "s_and_b64 vcc, vcc, s[20:21]\n\t"
        "v_cmp_eq_u32 s[20:21], %[w], v59\n\t"
        "s_and_b64 vcc, vcc, s[20:21]\n\t"
        "v_cmp_eq_u32 s[20:21], %[w], v61\n\t"
        "s_and_b64 vcc, vcc, s[20:21]\n\t"
        "v_cmp_eq_u32 s[20:21], %[w], v63\n\t"
        "s_and_b64 vcc, vcc, s[20:21]\n\t"
        "s_andn2_b64 s[20:21], exec, vcc\n\t"
        "s_cbranch_scc0 4f\n\t"             // B valid
        "global_load_dwordx4 v[48:51], %[p], off sc1\n\t"
        "global_load_dwordx4 v[52:55], %[p], off offset:16 sc1\n\t"
        "global_load_dwordx4 v[56:59], %[p], off offset:32 sc1\n\t"
        "global_load_dwordx4 v[60:63], %[p], off offset:48 sc1\n\t"
        "s_branch 1b\n\t"
        "4:\n\t"                            // B valid (A' in flight)
        "v_mov_b32 %[h0], v48\n\t"
        "v_mov_b32 %[h1], v50\n\t"
        "v_mov_b32 %[h2], v52\n\t"
        "v_mov_b32 %[h3], v54\n\t"
        "v_mov_b32 %[h4], v56\n\t"
        "v_mov_b32 %[h5], v58\n\t"
        "v_mov_b32 %[h6], v60\n\t"
        "v_mov_b32 %[h7], v62\n\t"
        "s_branch 5f\n\t"
        "3:\n\t"                            // A valid (B in flight)
        "v_mov_b32 %[h0], v32\n\t"
        "v_mov_b32 %[h1], v34\n\t"
        "v_mov_b32 %[h2], v36\n\t"
        "v_mov_b32 %[h3], v38\n\t"
        "v_mov_b32 %[h4], v40\n\t"
        "v_mov_b32 %[h5], v42\n\t"
        "v_mov_b32 %[h6], v44\n\t"
        "v_mov_b32 %[h7], v46\n\t"
        "5:\n\t"
        : [h0]"=v"(h0), [h1]"=v"(h1), [h2]"=v"(h2), [h3]"=v"(h3),
          [h4]"=v"(h4), [h5]"=v"(h5), [h6]"=v"(h6), [h7]"=v"(h7)
        : [p]"v"(p), [w]"v"(want)
        : "v32","v33","v34","v35","v36","v37","v38","v39",
          "v40","v41","v42","v43","v44","v45","v46","v47",
          "v48","v49","v50","v51","v52","v53","v54","v55",
          "v56","v57","v58","v59","v60","v61","v62","v63",
          "s20","s21","vcc","memory");
}

// -------------------------------------------------------------------------
// Kernel 1: G[dir][t][row] = Wih_dir[row,:] . embed[sent[t],:] + bih + bhh
// 128x128 tile, K-tile 16, 8x8 micro-tile -> 64 fmac per 4 ds_read_b128
// (fmac-bound; old 64x64/4x4 was LDS-issue-bound at ~2:1). K-accumulation
// order per output element is unchanged (strictly ascending k, fmac) ->
// G is bit-identical to the previous kernel's output.
// grid (TLEN/128, R4/128, 2), block 256.
// -------------------------------------------------------------------------
__global__ __launch_bounds__(256) void input_gemm(
    const int* __restrict__ sent, const float* __restrict__ embed,
    const float* __restrict__ WihF, const float* __restrict__ WihB,
    const float* __restrict__ bihF, const float* __restrict__ bhhF,
    const float* __restrict__ bihB, const float* __restrict__ bhhB,
    float* __restrict__ G)
{
    __shared__ float As[16][128];   // [k][t]  8 KB
    __shared__ float Bs[16][128];   // [k][n]  8 KB
    const int tid = threadIdx.x;
    const int tm = blockIdx.x * 128;
    const int tn = blockIdx.y * 128;
    const int dir = blockIdx.z;
    const float* Wih = dir ? WihB : WihF;

    const int lr = tid >> 1;            // 0..127 loader row
    const int lp = (tid & 1) * 8;       // k-part (8 floats)
    const int srow = sent[tm + lr];
    const float* arow = embed + (size_t)srow * EMB + lp;
    const float* brow = Wih + (size_t)(tn + lr) * EMB + lp;

    const int mt = (tid & 15) * 8;      // t micro offset
    const int nt = (tid >> 4) * 8;      // n micro offset
    float acc[8][8] = {};

    for (int k0 = 0; k0 < EMB; k0 += 16) {
        float4 a0 = *(const float4*)(arow + k0);
        float4 a1 = *(const float4*)(arow + k0 + 4);
        float4 b0 = *(const float4*)(brow + k0);
        float4 b1 = *(const float4*)(brow + k0 + 4);
        __syncthreads();
        As[lp + 0][lr] = a0.x; As[lp + 1][lr] = a0.y;
        As[lp + 2][lr] = a0.z; As[lp + 3][lr] = a0.w;
        As[lp + 4][lr] = a1.x; As[lp + 5][lr] = a1.y;
        As[lp + 6][lr] = a1.z; As[lp + 7][lr] = a1.w;
        Bs[lp + 0][lr] = b0.x; Bs[lp + 1][lr] = b0.y;
        Bs[lp + 2][lr] = b0.z; Bs[lp + 3][lr] = b0.w;
        Bs[lp + 4][lr] = b1.x; Bs[lp + 5][lr] = b1.y;
        Bs[lp + 6][lr] = b1.z; Bs[lp + 7][lr] = b1.w;
        __syncthreads();
        #pragma unroll
        for (int k = 0; k < 16; ++k) {
            float4 av0 = *(const float4*)(&As[k][mt]);
            float4 av1 = *(const float4*)(&As[k][mt + 4]);
            float4 bv0 = *(const float4*)(&Bs[k][nt]);
            float4 bv1 = *(const float4*)(&Bs[k][nt + 4]);
            float am[8] = {av0.x, av0.y, av0.z, av0.w, av1.x, av1.y, av1.z, av1.w};
            float bb[8] = {bv0.x, bv0.y, bv0.z, bv0.w, bv1.x, bv1.y, bv1.z, bv1.w};
            #pragma unroll
            for (int i = 0; i < 8; ++i) {
                #pragma unroll
                for (int j = 0; j < 8; ++j) acc[i][j] += am[i] * bb[j];
            }
        }
    }

    const float* bih = dir ? bihB : bihF;
    const float* bhh = dir ? bhhB : bhhF;
    float bias[8];
    #pragma unroll
    for (int j = 0; j < 8; ++j) bias[j] = bih[tn + nt + j] + bhh[tn + nt + j];
    float* Gd = G + (size_t)dir * TLEN * R4;
    #pragma unroll
    for (int i = 0; i < 8; ++i) {
        float4 o0, o1;
        o0.x = acc[i][0] + bias[0]; o0.y = acc[i][1] + bias[1];
        o0.z = acc[i][2] + bias[2]; o0.w = acc[i][3] + bias[3];
        o1.x = acc[i][4] + bias[4]; o1.y = acc[i][5] + bias[5];
        o1.z = acc[i][6] + bias[6]; o1.w = acc[i][7] + bias[7];
        float* orow = Gd + (size_t)(tm + mt + i) * R4 + tn + nt;
        *(float4*)(orow) = o0;
        *(float4*)(orow + 4) = o1;
    }
}

// -------------------------------------------------------------------------
// Kernel 2: persistent BiLSTM recurrence — agent-scope mailbox, round-5
// structure with the three compiled-code leaks fixed:
//  - RAW s_barrier + lgkmcnt(0)-only drain: hipcc's __syncthreads emits
//    s_waitcnt vmcnt(0) before s_barrier, which drained the spin's
//    in-flight poll group (+~400cyc/step, all waves). sched_barrier(0)
//    after the barrier pins ordering (rule-18-style safety, compile-time).
//  - spin has no entry vmcnt(0) drain (see spin64 comment)
//  - W pinned as 64 SCALAR floats via per-element empty asm (round-5's
//    VGPR_Count=72 proved the weights were re-streamed from memory inside
//    every dot; round-6's float4 "+v" pin was an unsupported tied-vector
//    constraint -> scalar ties, the supported pattern)
// -------------------------------------------------------------------------
__global__ __launch_bounds__(512, 1) void lstm_rec(
    const float* __restrict__ WhhF, const float* __restrict__ WhhB,
    const float* __restrict__ h0, const float* __restrict__ c0,
    const float* __restrict__ G, float* __restrict__ hs,
    u64* hbuf)
{
    const int tid  = threadIdx.x;
    const int dir  = blockIdx.x >> 5;
    const int wg   = blockIdx.x & 31;
    const int base = wg * SLICE;
    const int wave = tid >> 6;
    const int wl   = tid & 63;
    const int half = wl >> 5;             // h-elem within wave
    const int gp   = (wl >> 4) & 1;       // gate-row pair selector
    const int qs   = wl & 15;             // 32-col segment
    const int e    = wave * 2 + half;     // 0..15, h-elem within WG slice
    const int grow0 = gp * H2 + base + e;          // gate gp   (0:i or 1:f)
    const int grow1 = (gp + 2) * H2 + base + e;    // gate gp+2 (2:g or 3:o)
    const bool prod = (wl & 31) == 0;     // gp==0 && qs==0
    const float* Whh = dir ? WhhB : WhhF;

    // Weights in registers: two 32-col row segments, held as 64 scalar
    // floats and PINNED via empty asm so the allocator cannot re-stream
    // them from memory inside the (latency-critical) dot.
    float W0s[32], W1s[32];
    {
        const float4* s0 = (const float4*)(Whh + (size_t)grow0 * H2 + qs * 32);
        const float4* s1 = (const float4*)(Whh + (size_t)grow1 * H2 + qs * 32);
        #pragma unroll
        for (int j = 0; j < 8; ++j) {
            float4 a = s0[j], b = s1[j];
            W0s[4*j+0] = a.x; W0s[4*j+1] = a.y; W0s[4*j+2] = a.z; W0s[4*j+3] = a.w;
            W1s[4*j+0] = b.x; W1s[4*j+1] = b.y; W1s[4*j+2] = b.z; W1s[4*j+3] = b.w;
        }
        #pragma unroll
        for (int j = 0; j < 32; ++j) {
            asm volatile("" : "+v"(W0s[j]), "+v"(W1s[j]));
        }
    }

    // h staged as 8 segments of 64 floats, pitch 68 (bank-quad tiling);
    // double-buffered by step parity -> one barrier per step.
    __shared__ float hsh[2][8 * 68];

    u64* hb = hbuf + (size_t)dir * 2 * H2;  // [parity][512] tagged slots
    float cc = 0.f;
    if (prod) {
        cc = c0[dir * H2 + base + e];
        float hv = h0[dir * H2 + base + e];
        u64 pack = ((u64)1u << 32) | (u64)__float_as_uint(hv);  // tag 1 = h(0)
        ASTORE64(hb + base + e, pack);      // parity 0
    }

    const float* Gd = G + (size_t)dir * TLEN * R4;
    float* hsd = hs + (size_t)dir * TLEN * H2;
    const ptrdiff_t sstep = dir ? -(ptrdiff_t)R4 : (ptrdiff_t)R4;
    const float* g0p = Gd + (size_t)(dir ? TLEN - 1 : 0) * R4;  // row for s=0

    // Wave-0 detector pointers: lane wl owns slots [wl*8, wl*8+8)
    const u64* pollP0 = hb + wl * 8;        // parity 0 (64B aligned)
    const u64* pollP1 = hb + H2 + wl * 8;   // parity 1

    // Prologue G prefetch for s=0 (even regs) and s=1 (odd regs)
    float gE0 = g0p[grow0], gE1 = g0p[grow1];
    float gO0 = (g0p + sstep)[grow0], gO1 = (g0p + sstep)[grow1];

#define STEP(S, PAR, GR0, GR1)                                                \
  {                                                                           \
    if (wave == 0) {                                                          \
        unsigned x0, x1, x2, x3, x4, x5, x6, x7;                              \
        spin64((PAR) ? pollP1 : pollP0, (unsigned)((S) + 1),                  \
               x0, x1, x2, x3, x4, x5, x6, x7);                               \
        float4 f0, f1;                                                        \
        f0.x = __uint_as_float(x0); f0.y = __uint_as_float(x1);               \
        f0.z = __uint_as_float(x2); f0.w = __uint_as_float(x3);               \
        f1.x = __uint_as_float(x4); f1.y = __uint_as_float(x5);               \
        f1.z = __uint_as_float(x6); f1.w = __uint_as_float(x7);               \
        float4* dst = (float4*)&hsh[PAR][(wl >> 3) * 68 + (wl & 7) * 8];      \
        dst[0] = f0; dst[1] = f1;                                             \
    }                                                                         \
    /* raw barrier: LDS drain only — do NOT let __syncthreads' vmcnt(0)  */   \
    /* drain the spin's in-flight poll group / G loads / store-acks.     */   \
    asm volatile("s_waitcnt lgkmcnt(0)" ::: "memory");                        \
    __builtin_amdgcn_s_barrier();                                             \
    __builtin_amdgcn_sched_barrier(0);  /* pin post-barrier loads below */    \
    const float gc0 = GR0, gc1 = GR1;   /* consume-copy */                    \
    {   /* distance-2 reload issued early: full dot-phase of latency slack */ \
        const int sn = ((S) + 2 < TLEN) ? (S) + 2 : TLEN - 1;                 \
        const float* gn = g0p + (ptrdiff_t)sn * sstep;                        \
        GR0 = gn[grow0]; GR1 = gn[grow1];                                     \
    }                                                                         \
    const float4* hq = (const float4*)(&hsh[PAR][(qs >> 1) * 68 + (qs & 1) * 32]); \
    float p00 = 0.f, p01 = 0.f, p02 = 0.f, p03 = 0.f;                         \
    float p10 = 0.f, p11 = 0.f, p12 = 0.f, p13 = 0.f;                         \
    _Pragma("unroll")                                                         \
    for (int j = 0; j < 8; ++j) {                                             \
        float4 h4 = hq[j];                                                    \
        p00 += W0s[4*j+0] * h4.x; p01 += W0s[4*j+1] * h4.y;                   \
        p02 += W0s[4*j+2] * h4.z; p03 += W0s[4*j+3] * h4.w;                   \
        p10 += W1s[4*j+0] * h4.x; p11 += W1s[4*j+1] * h4.y;                   \
        p12 += W1s[4*j+2] * h4.z; p13 += W1s[4*j+3] * h4.w;                   \
    }                                                                         \
    float t0 = (p00 + p01) + (p02 + p03);                                     \
    float t1 = (p10 + p11) + (p12 + p13);                                     \
    t0 += __shfl_xor(t0, 1); t0 += __shfl_xor(t0, 2);                         \
    t0 += __shfl_xor(t0, 4); t0 += __shfl_xor(t0, 8);                         \
    t1 += __shfl_xor(t1, 1); t1 += __shfl_xor(t1, 2);                         \
    t1 += __shfl_xor(t1, 4); t1 += __shfl_xor(t1, 8);                         \
    t0 += gc0;                          /* loaded 2 steps ago: no wait */     \
    t1 += gc1;                                                                \
    float pf = __shfl_xor(t0, 16);      /* gate 1 (f) from gp-partner */      \
    float po = __shfl_xor(t1, 16);      /* gate 3 (o) */                      \
    if (prod) {                          /* lane holds gate0 (i), gate2 (g) */\
        float i_ = fsig(t0);                                                  \
        float f_ = fsig(pf);                                                  \
        float g_ = ftanh(t1);                                                 \
        float o_ = fsig(po);                                                  \
        cc = f_ * cc + i_ * g_;                                               \
        float hn = o_ * ftanh(cc);                                            \
        u64 pack = ((u64)(unsigned)((S) + 2) << 32) | (u64)__float_as_uint(hn); \
        ASTORE64(hb + (1 - (PAR)) * H2 + base + e, pack);                     \
        hsd[(size_t)(dir ? (TLEN - 1 - (S)) : (S)) * H2 + base + e] = hn;     \
    }                                                                         \
    /* no trailing barrier: hsh is parity-double-buffered; the single    */   \
    /* per-step barrier bounds intra-WG wave skew to 1 step.             */   \
  }

    for (int s = 0; s < TLEN; s += 2) {
        STEP(s,     0, gE0, gE1);
        STEP(s + 1, 1, gO0, gO1);
    }
#undef STEP
}

// -------------------------------------------------------------------------
// Kernel 3: feats[t][j] = concat(hf[t], hb[t]) . Wout[j] + bout[j]
// -------------------------------------------------------------------------
__global__ __launch_bounds__(64) void feat_kernel(
    const float* __restrict__ hs, const float* __restrict__ Wout,
    const float* __restrict__ bout, float* __restrict__ feats)
{
    const int t = blockIdx.x;
    const int lane = threadIdx.x;
    const float* hf = hs + (size_t)t * H2;
    const float* hb = hs + (size_t)TLEN * H2 + (size_t)t * H2;
    float x[16];
    #pragma unroll
    for (int r = 0; r < 8; ++r) x[r] = hf[lane + r * 64];
    #pragma unroll
    for (int r = 0; r < 8; ++r) x[8 + r] = hb[lane + r * 64];
    for (int j = 0; j < NTAGS; ++j) {
        const float* wr = Wout + (size_t)j * EMB;
        float p = 0.f;
        #pragma unroll
        for (int r = 0; r < 8; ++r) p += x[r] * wr[lane + r * 64];
        #pragma unroll
        for (int r = 0; r < 8; ++r) p += x[8 + r] * wr[H2 + lane + r * 64];
        #pragma unroll
        for (int off = 32; off > 0; off >>= 1) p += __shfl_down(p, off);
        if (lane == 0) feats[t * NTAGS + j] = p + bout[j];
    }
}

// -------------------------------------------------------------------------
// Kernel 4: Viterbi forward scan + backtrace, single wave.
// -------------------------------------------------------------------------
__global__ __launch_bounds__(64) void viterbi_kernel(
    const float* __restrict__ feats, const float* __restrict__ trans,
    float* __restrict__ out)
{
    __shared__ unsigned bp[TLEN];       // 16 KB packed backpointers
    __shared__ float fch[256 * NTAGS];  // feats chunk (5 KB)
    const int lane = threadIdx.x;
    const bool act = lane < 25;
    const int j = act ? (lane / 5) : 0;
    const int i = act ? (lane % 5) : 0;
    const int j5 = j * 5;
    const float tji = act ? trans[j * 5 + i] : -1e30f;
    float fv = (i == STARTT) ? 0.f : NEGV;

    for (int c0 = 0; c0 < TLEN; c0 += 256) {
        __syncthreads();
        for (int m = lane; m < 256 * NTAGS; m += 64) fch[m] = feats[c0 * NTAGS + m];
        __syncthreads();
        for (int tt = 0; tt < 256; ++tt) {
            float score = fv + tji;
            float v0 = __shfl(score, j5 + 0);
            float v1 = __shfl(score, j5 + 1);
            float v2 = __shfl(score, j5 + 2);
            float v3 = __shfl(score, j5 + 3);
            float v4 = __shfl(score, j5 + 4);
            float mm = v0; int mi = 0;                 // first-max (jnp.argmax)
            if (v1 > mm) { mm = v1; mi = 1; }
            if (v2 > mm) { mm = v2; mi = 2; }
            if (v3 > mm) { mm = v3; mi = 3; }
            if (v4 > mm) { mm = v4; mi = 4; }
            float fnew = mm + fch[tt * NTAGS + j];
            unsigned word = ((unsigned)__shfl(mi, 0)  & 7u)
                          | (((unsigned)__shfl(mi, 5)  & 7u) << 3)
                          | (((unsigned)__shfl(mi, 10) & 7u) << 6)
                          | (((unsigned)__shfl(mi, 15) & 7u) << 9)
                          | (((unsigned)__shfl(mi, 20) & 7u) << 12);
            if (lane == 0) bp[c0 + tt] = word;
            fv = __shfl(fnew, i * 5);
        }
    }
    __syncthreads();

    float tstop = (lane < 5) ? trans[STOPT * 5 + lane] : -1e30f;
    float term = fv + tstop;
    float b0 = __shfl(term, 0), b1 = __shfl(term, 1), b2 = __shfl(term, 2);
    float b3 = __shfl(term, 3), b4 = __shfl(term, 4);
    float bsc = b0; int best = 0;
    if (b1 > bsc) { bsc = b1; best = 1; }
    if (b2 > bsc) { bsc = b2; best = 2; }
    if (b3 > bsc) { bsc = b3; best = 3; }
    if (b4 > bsc) { bsc = b4; best = 4; }

    if (lane == 0) {
        out[0] = bsc;                       // path_score
        int tag = best;
        out[TLEN] = (float)tag;             // best_path[T-1]
        #pragma unroll 16
        for (int t = TLEN - 1; t >= 1; --t) {
            tag = (int)((bp[t] >> (3 * tag)) & 7u);
            out[t] = (float)tag;            // best_path[t-1] at out[1+(t-1)]
        }
    }
}

// -------------------------------------------------------------------------
// Launcher
// -------------------------------------------------------------------------
extern "C" void kernel_launch(void* const* d_in, const int* in_sizes, int n_in,
                              void* d_out, int out_size, void* d_ws, size_t ws_size,
                              hipStream_t stream) {
    const int*   sent  = (const int*)d_in[0];
    const float* h0    = (const float*)d_in[1];
    const float* c0    = (const float*)d_in[2];
    const float* embed = (const float*)d_in[3];
    const float* Wih_f = (const float*)d_in[4];
    const float* Whh_f = (const float*)d_in[5];
    const float* bih_f = (const float*)d_in[6];
    const float* bhh_f = (const float*)d_in[7];
    const float* Wih_b = (const float*)d_in[8];
    const float* Whh_b = (const float*)d_in[9];
    const float* bih_b = (const float*)d_in[10];
    const float* bhh_b = (const float*)d_in[11];
    const float* Wout  = (const float*)d_in[12];
    const float* bout  = (const float*)d_in[13];
    const float* trans = (const float*)d_in[14];

    char* ws = (char*)d_ws;
    float*    G     = (float*)(ws);                 // 2*4096*2048 f32 = 64 MB
    float*    hs    = (float*)(ws + 67108864);      // 2*4096*512  f32 = 16 MB
    u64*      hbuf  = (u64*)(ws + 83886080);        // 2 dirs * 2 parity * 512 u64 = 16 KB
    float*    feats = (float*)(ws + 83918848);      // 4096*5 f32

    // Zero the mailbox: stale tags from a previous replay must not satisfy
    // any step's spin early.
    hipMemsetAsync(hbuf, 0, 2 * 2 * H2 * sizeof(u64), stream);

    input_gemm<<<dim3(TLEN / 128, R4 / 128, 2), 256, 0, stream>>>(
        sent, embed, Wih_f, Wih_b, bih_f, bhh_f, bih_b, bhh_b, G);
    lstm_rec<<<2 * DWG, 512, 0, stream>>>(Whh_f, Whh_b, h0, c0, G, hs, hbuf);
    feat_kernel<<<TLEN, 64, 0, stream>>>(hs, Wout, bout, feats);
    viterbi_kernel<<<1, 64, 0, stream>>>(feats, trans, (float*)d_out);
}